// Round 1
// baseline (210.943 us; speedup 1.0000x reference)
//
#include <hip/hip_runtime.h>
#include <stdint.h>

// LocalAggregation (PointNet++ SA layer, B=4 N=4096 C=32 K=32, 35->64->64)
//
// Pipeline:
//  K1 ballquery : idx[b][n][32]  (first 32 ascending j with d2<0.01, pad=first)
//  Kt transpose : W1t[35][64], W2t[64][64]
//  K2 uq        : u[b][n][64] = W1[:,3:]x + W1[:,:3]p ; q = W1[:,:3]p   (y1 = u[j]-q[n])
//  K3 bn1 stats : per-channel sum/sumsq of y1 -> partials
//  Kf finalize  : a1 = g/sqrt(var+eps), c1 = b - a1*mean
//  K4 apply     : u <- a1*u ; q <- a1*q - c1   (so h = relu(u[j]-q[n]))
//  K5 stage2    : y2 = W2*h per sample; per-(n,o) max/min over k; global sum/sumsq
//  Kf finalize  : a2,c2
//  K6 out       : out[b][o][n] = relu(a2*(a2>=0?max:min) + c2)

#define N_PTS 4096
#define R2 0.01f

__device__ __forceinline__ uint32_t pack_bf16(float a, float b) {
  uint32_t ua = __float_as_uint(a), ub = __float_as_uint(b);
  ua += 0x7fffu + ((ua >> 16) & 1u);
  ub += 0x7fffu + ((ub >> 16) & 1u);
  return (ua >> 16) | (ub & 0xffff0000u);
}

// ---------------- K1: ball query ----------------
__global__ __launch_bounds__(512) void k_ballquery(const float* __restrict__ p,
                                                   int* __restrict__ idx) {
  __shared__ float pl[N_PTS * 3];
  const int b = blockIdx.x >> 9;              // 512 blocks per batch
  const int nb = (blockIdx.x & 511) << 3;     // 8 points per block (1/wave)
  const float* pb = p + b * (N_PTS * 3);
  for (int i = threadIdx.x; i < N_PTS * 3; i += 512) pl[i] = pb[i];
  __syncthreads();
  const int wv = threadIdx.x >> 6, lane = threadIdx.x & 63;
  const int n = nb + wv;
  const float px = pl[n * 3], py = pl[n * 3 + 1], pz = pl[n * 3 + 2];
  int* row = idx + (((b << 12) + n) << 5);
  int cnt = 0, first = 0;
  for (int jb = 0; jb < N_PTS; jb += 64) {
    const int j = jb + lane;
    const float dx = pl[j * 3] - px, dy = pl[j * 3 + 1] - py, dz = pl[j * 3 + 2] - pz;
    // match numpy fp32 (no fma contraction, same summation order)
    const float d2 = __fadd_rn(__fadd_rn(__fmul_rn(dx, dx), __fmul_rn(dy, dy)),
                               __fmul_rn(dz, dz));
    const bool hit = d2 < R2;
    const unsigned long long m = __ballot(hit);
    if (m) {
      if (cnt == 0) first = jb + (int)__builtin_ctzll(m);
      const int below = (int)__popcll(m & ((1ull << lane) - 1ull));
      if (hit && (cnt + below) < 32) row[cnt + below] = j;
      cnt += (int)__popcll(m);
      if (cnt >= 32) break;   // uniform
    }
  }
  for (int s = cnt + lane; s < 32; s += 64) row[s] = first;
}

// ---------------- Kt: weight transposes ----------------
__global__ void k_transpose(const float* __restrict__ W1, const float* __restrict__ W2,
                            float* __restrict__ W1t, float* __restrict__ W2t) {
  const int t = blockIdx.x * 256 + threadIdx.x;
  if (t < 64 * 35) { int o = t / 35, c = t - o * 35; W1t[(c << 6) + o] = W1[t]; }
  if (t < 4096)    { int o = t >> 6, c = t & 63;     W2t[(c << 6) + o] = W2[t]; }
}

// ---------------- K2: u, q per point ----------------
__global__ __launch_bounds__(64) void k_uq(const float* __restrict__ p,
                                           const float* __restrict__ x,
                                           const float* __restrict__ W1t,
                                           float* __restrict__ u, float* __restrict__ q) {
  const int b = blockIdx.x >> 6;
  const int n = ((blockIdx.x & 63) << 6) + (int)threadIdx.x;
  const int pn = (b << 12) + n;
  float f[35];
  const float* pb = p + pn * 3;
  f[0] = pb[0]; f[1] = pb[1]; f[2] = pb[2];
  const float* xb = x + (b << 17) + n;
#pragma unroll
  for (int c = 0; c < 32; ++c) f[3 + c] = xb[c << 12];
  float acc[64];
#pragma unroll
  for (int o = 0; o < 64; ++o) acc[o] = 0.f;
#pragma unroll
  for (int c = 0; c < 35; ++c) {
    const float fc = f[c];
    const float4* w4 = (const float4*)(W1t + (c << 6));
#pragma unroll
    for (int o4 = 0; o4 < 16; ++o4) {
      float4 wv = w4[o4];
      acc[4 * o4 + 0] = fmaf(wv.x, fc, acc[4 * o4 + 0]);
      acc[4 * o4 + 1] = fmaf(wv.y, fc, acc[4 * o4 + 1]);
      acc[4 * o4 + 2] = fmaf(wv.z, fc, acc[4 * o4 + 2]);
      acc[4 * o4 + 3] = fmaf(wv.w, fc, acc[4 * o4 + 3]);
    }
    if (c == 2) {  // q = first-3 partial
      float4* qr = (float4*)(q + (pn << 6));
#pragma unroll
      for (int o4 = 0; o4 < 16; ++o4)
        qr[o4] = make_float4(acc[4 * o4], acc[4 * o4 + 1], acc[4 * o4 + 2], acc[4 * o4 + 3]);
    }
  }
  float4* ur = (float4*)(u + (pn << 6));
#pragma unroll
  for (int o4 = 0; o4 < 16; ++o4)
    ur[o4] = make_float4(acc[4 * o4], acc[4 * o4 + 1], acc[4 * o4 + 2], acc[4 * o4 + 3]);
}

// ---------------- K3: BN1 stats (lane = channel) ----------------
__global__ __launch_bounds__(256) void k_bn1(const float* __restrict__ u,
                                             const float* __restrict__ q,
                                             const int* __restrict__ idx,
                                             float* __restrict__ part1) {
  const int gw = (blockIdx.x << 2) + (threadIdx.x >> 6);  // 1024 waves
  const int lane = threadIdx.x & 63;
  float s1 = 0.f, s2 = 0.f;
  const int base = gw << 4;  // 16 points per wave
  for (int t = 0; t < 16; ++t) {
    const int pn = base + t;
    const float qv = q[(pn << 6) + lane];
    const int* irow = idx + (pn << 5);
    int myj = (lane < 32) ? irow[lane] : 0;
    const int bb = (pn >> 12) << 12;
#pragma unroll 8
    for (int k = 0; k < 32; ++k) {
      int jj = __shfl(myj, k);
      float y = u[((bb + jj) << 6) + lane] - qv;
      s1 += y;
      s2 = fmaf(y, y, s2);
    }
  }
  part1[lane * 1024 + gw] = s1;
  part1[(64 + lane) * 1024 + gw] = s2;
}

// ---------------- Kf: reduce partials, finalize BN affine ----------------
__global__ __launch_bounds__(128) void k_finalize(const float* __restrict__ part, int cols,
                                                  float invM, const float* __restrict__ g,
                                                  const float* __restrict__ bb,
                                                  float* __restrict__ ac) {
  const int ch = blockIdx.x;           // 64 blocks
  const int t = threadIdx.x;           // 128 = 2 waves
  const int half = t >> 6, lane = t & 63;
  const float4* r4 = (const float4*)(part + (size_t)(ch + half * 64) * cols);
  float s = 0.f;
  for (int i = lane; i < (cols >> 2); i += 64) {
    float4 v = r4[i];
    s += v.x + v.y + v.z + v.w;
  }
  for (int d = 32; d; d >>= 1) s += __shfl_xor(s, d);
  __shared__ float ls[2];
  if (lane == 0) ls[half] = s;
  __syncthreads();
  if (t == 0) {
    float mean = ls[0] * invM;
    float var = ls[1] * invM - mean * mean;
    float a = g[ch] * rsqrtf(var + 1e-5f);
    ac[ch] = a;
    ac[64 + ch] = bb[ch] - mean * a;
  }
}

// ---------------- K4: fold BN1 affine into u,q ----------------
__global__ __launch_bounds__(256) void k_apply(float* __restrict__ u, float* __restrict__ q,
                                               const float* __restrict__ ac) {
  const int i = blockIdx.x * 256 + threadIdx.x;  // float4 index, 262144 total
  const int c4 = i & 15;
  const float4 a = ((const float4*)ac)[c4];
  const float4 cc = ((const float4*)(ac + 64))[c4];
  float4* u4 = (float4*)u;
  float4* q4 = (float4*)q;
  float4 uu = u4[i], qq = q4[i];
  uu.x *= a.x; uu.y *= a.y; uu.z *= a.z; uu.w *= a.w;
  qq.x = fmaf(qq.x, a.x, -cc.x);
  qq.y = fmaf(qq.y, a.y, -cc.y);
  qq.z = fmaf(qq.z, a.z, -cc.z);
  qq.w = fmaf(qq.w, a.w, -cc.w);
  u4[i] = uu; q4[i] = qq;
}

// ---------------- K5: conv2 + per-(n,o) max/min over k + BN2 partials ----------------
__global__ __launch_bounds__(256) void k_stage2(const float* __restrict__ u,
                                                const float* __restrict__ q,
                                                const int* __restrict__ idx,
                                                const float* __restrict__ W2t,
                                                float* __restrict__ part2,
                                                float* __restrict__ ymax,
                                                float* __restrict__ ymin) {
  __shared__ uint32_t hl[4][2048];  // 8KB per wave: h (bf16x2), then y2 reduce buffer
  const int tid = threadIdx.x;
  const int w = tid >> 6, lw = tid & 63;
  const int sg = blockIdx.x * 256 + tid;           // sample id, k fastest
  const int b = sg >> 17;
  const int r = sg & 131071;
  const int n = r >> 5, k = r & 31;
  const int pn = (b << 12) + n;
  const int j = idx[(pn << 5) + k];
  const float4* up = (const float4*)(u + (((b << 12) + j) << 6));
  const float4* qp = (const float4*)(q + (pn << 6));
  uint32_t* hw = hl[w];
  // phase 1: h = relu(u~[j] - q~[n]) -> LDS bf16 pairs, layout [c2][64 lanes]
#pragma unroll
  for (int c4 = 0; c4 < 16; ++c4) {
    float4 uu = up[c4], qq = qp[c4];
    float h0 = fmaxf(uu.x - qq.x, 0.f);
    float h1 = fmaxf(uu.y - qq.y, 0.f);
    float h2 = fmaxf(uu.z - qq.z, 0.f);
    float h3 = fmaxf(uu.w - qq.w, 0.f);
    hw[(2 * c4) * 64 + lw] = pack_bf16(h0, h1);
    hw[(2 * c4 + 1) * 64 + lw] = pack_bf16(h2, h3);
  }
  __syncthreads();
  // phase 2: y2[o] = sum_c W2t[c][o]*h[c]
  float acc[64];
#pragma unroll
  for (int o = 0; o < 64; ++o) acc[o] = 0.f;
#pragma unroll 2
  for (int c2 = 0; c2 < 32; ++c2) {
    uint32_t hp = hw[c2 * 64 + lw];
    float h0 = __uint_as_float(hp << 16);
    float h1 = __uint_as_float(hp & 0xffff0000u);
    const float4* w40 = (const float4*)(W2t + (c2 * 2) * 64);     // uniform -> s_load
    const float4* w41 = (const float4*)(W2t + (c2 * 2 + 1) * 64);
#pragma unroll
    for (int o4 = 0; o4 < 16; ++o4) {
      float4 wa = w40[o4], wb = w41[o4];
      acc[4 * o4 + 0] = fmaf(wa.x, h0, acc[4 * o4 + 0]);
      acc[4 * o4 + 1] = fmaf(wa.y, h0, acc[4 * o4 + 1]);
      acc[4 * o4 + 2] = fmaf(wa.z, h0, acc[4 * o4 + 2]);
      acc[4 * o4 + 3] = fmaf(wa.w, h0, acc[4 * o4 + 3]);
      acc[4 * o4 + 0] = fmaf(wb.x, h1, acc[4 * o4 + 0]);
      acc[4 * o4 + 1] = fmaf(wb.y, h1, acc[4 * o4 + 1]);
      acc[4 * o4 + 2] = fmaf(wb.z, h1, acc[4 * o4 + 2]);
      acc[4 * o4 + 3] = fmaf(wb.w, h1, acc[4 * o4 + 3]);
    }
  }
  __syncthreads();
  // phase 3: y2 -> LDS bf16 pairs, [n_loc][o2][k] with XOR swizzle on k-quads
  {
    const int nl = lw >> 5, kk = lw & 31, kq = kk >> 2, kl = kk & 3;
#pragma unroll
    for (int o2 = 0; o2 < 32; ++o2) {
      int a = nl * 1024 + o2 * 32 + (((kq ^ (o2 & 7)) << 2) | kl);
      hw[a] = pack_bf16(acc[2 * o2], acc[2 * o2 + 1]);
    }
  }
  __syncthreads();
  // phase 4: per (n_loc, o-pair) reduce over k: max/min + sum/sumsq
  const int o2r = lw & 31, nr = lw >> 5;
  float mx0 = -3e38f, mx1 = -3e38f, mn0 = 3e38f, mn1 = 3e38f;
  float s0 = 0.f, s1 = 0.f, t0 = 0.f, t1 = 0.f;
#pragma unroll
  for (int kq2 = 0; kq2 < 8; ++kq2) {
    uint4 d = *(const uint4*)&hw[nr * 1024 + o2r * 32 + ((kq2 ^ (o2r & 7)) << 2)];
    uint32_t dd[4] = {d.x, d.y, d.z, d.w};
#pragma unroll
    for (int e = 0; e < 4; ++e) {
      float v0 = __uint_as_float(dd[e] << 16);
      float v1 = __uint_as_float(dd[e] & 0xffff0000u);
      mx0 = fmaxf(mx0, v0); mn0 = fminf(mn0, v0);
      mx1 = fmaxf(mx1, v1); mn1 = fminf(mn1, v1);
      s0 += v0; s1 += v1;
      t0 = fmaf(v0, v0, t0); t1 = fmaf(v1, v1, t1);
    }
  }
  const int sgw = blockIdx.x * 256 + w * 64;
  const int bW = sgw >> 17;
  const int nW = (sgw & 131071) >> 5;
  const int pn2 = (bW << 12) + nW + nr;
  *(float2*)&ymax[(pn2 << 6) + 2 * o2r] = make_float2(mx0, mx1);
  *(float2*)&ymin[(pn2 << 6) + 2 * o2r] = make_float2(mn0, mn1);
  s0 += __shfl_xor(s0, 32); s1 += __shfl_xor(s1, 32);
  t0 += __shfl_xor(t0, 32); t1 += __shfl_xor(t1, 32);
  if (lw < 32) {
    const int col = blockIdx.x * 4 + w;  // 8192 wave columns
    part2[(2 * o2r) * 8192 + col] = s0;
    part2[(2 * o2r + 1) * 8192 + col] = s1;
    part2[(64 + 2 * o2r) * 8192 + col] = t0;
    part2[(64 + 2 * o2r + 1) * 8192 + col] = t1;
  }
}

// ---------------- K6: output ----------------
__global__ __launch_bounds__(256) void k_out(const float* __restrict__ ymax,
                                             const float* __restrict__ ymin,
                                             const float* __restrict__ ac,
                                             float* __restrict__ out) {
  const int i = blockIdx.x * 256 + threadIdx.x;  // i = pn*64 + o
  const int o = i & 63;
  const int pn = i >> 6;
  const int b = pn >> 12, n = pn & 4095;
  float a = ac[o], c = ac[64 + o];
  float v = (a >= 0.f) ? ymax[i] : ymin[i];
  out[(b << 18) + (o << 12) + n] = fmaxf(fmaf(a, v, c), 0.f);
}

extern "C" void kernel_launch(void* const* d_in, const int* in_sizes, int n_in,
                              void* d_out, int out_size, void* d_ws, size_t ws_size,
                              hipStream_t stream) {
  const float* p  = (const float*)d_in[0];
  const float* x  = (const float*)d_in[1];
  const float* W1 = (const float*)d_in[2];
  const float* g1 = (const float*)d_in[3];
  const float* b1 = (const float*)d_in[4];
  const float* W2 = (const float*)d_in[5];
  const float* g2 = (const float*)d_in[6];
  const float* b2 = (const float*)d_in[7];
  float* out = (float*)d_out;

  char* ws = (char*)d_ws;
  size_t off = 0;
  int* idx    = (int*)(ws + off);   off += 2097152;   // B*N*32 int
  float* u    = (float*)(ws + off); off += 4194304;   // B*N*64 f32
  float* q    = (float*)(ws + off); off += 4194304;
  float* W1t  = (float*)(ws + off); off += 16384;
  float* W2t  = (float*)(ws + off); off += 16384;
  float* part1= (float*)(ws + off); off += 524288;    // [128][1024]
  float* a1c1 = (float*)(ws + off); off += 1024;
  float* part2= (float*)(ws + off); off += 4194304;   // [128][8192]
  float* a2c2 = (float*)(ws + off); off += 1024;
  float* ymax = (float*)(ws + off); off += 4194304;   // [b][n][o]
  float* ymin = (float*)(ws + off); off += 4194304;   // total ~22.5 MB

  const float invM = 1.f / 524288.f;

  k_ballquery<<<dim3(2048), dim3(512), 0, stream>>>(p, idx);
  k_transpose<<<dim3(16), dim3(256), 0, stream>>>(W1, W2, W1t, W2t);
  k_uq<<<dim3(256), dim3(64), 0, stream>>>(p, x, W1t, u, q);
  k_bn1<<<dim3(256), dim3(256), 0, stream>>>(u, q, idx, part1);
  k_finalize<<<dim3(64), dim3(128), 0, stream>>>(part1, 1024, invM, g1, b1, a1c1);
  k_apply<<<dim3(1024), dim3(256), 0, stream>>>(u, q, a1c1);
  k_stage2<<<dim3(2048), dim3(256), 0, stream>>>(u, q, idx, W2t, part2, ymax, ymin);
  k_finalize<<<dim3(64), dim3(128), 0, stream>>>(part2, 8192, invM, g2, b2, a2c2);
  k_out<<<dim3(4096), dim3(256), 0, stream>>>(ymax, ymin, a2c2, out);
}

// Round 2
// 111.996 us; speedup vs baseline: 1.8835x; 1.8835x over previous
//
#include <hip/hip_runtime.h>
#include <stdint.h>

// LocalAggregation (PointNet++ SA layer, B=4 N=4096 C=32 K=32, 35->64->64)
//
//  K1 ballquery : idx[b][n][32] (first 32 ascending j with d2<0.01, pad=first)
//  Kp prep      : W1t[35][64]; W2 packed as bf16 MFMA B-fragments (8 frags)
//  K2 uq        : u[b][n][64] = W1[:,3:]x + W1[:,:3]p ; q = W1[:,:3]p  (y1 = u[j]-q[n])
//  K3 bn1 stats : per-channel sum/sumsq of y1 -> partials
//  Kf finalize  : a1 = g/sqrt(var+eps), c1 = b - a1*mean
//  K5 stage2    : h = relu(a1*(u[j]-q[n])+c1) -> LDS bf16 (swizzled);
//                 y2 = W2*h via mfma_16x16x32_bf16 (samples on M-axis);
//                 per-(n,o) max/min over k; BN2 sum/sumsq partials
//  Kf finalize  : a2,c2
//  K6 out       : out[b][o][n] = relu(a2*(a2>=0?max:min) + c2)

#define R2 0.01f

typedef __bf16 bf16x8 __attribute__((ext_vector_type(8)));
typedef float f32x4 __attribute__((ext_vector_type(4)));

__device__ __forceinline__ uint32_t pack_bf16(float a, float b) {
  uint32_t ua = __float_as_uint(a), ub = __float_as_uint(b);
  ua += 0x7fffu + ((ua >> 16) & 1u);
  ub += 0x7fffu + ((ub >> 16) & 1u);
  return (ua >> 16) | (ub & 0xffff0000u);
}

// ---------------- K1: ball query (transposed LDS, 2 pts/lane) ----------------
__global__ __launch_bounds__(1024) void k_ballquery(const float* __restrict__ p,
                                                    int* __restrict__ idx) {
  __shared__ float px[4096], py[4096], pz[4096];
  const int b = blockIdx.x >> 8;             // 256 blocks per batch
  const int nb = (blockIdx.x & 255) << 4;    // 16 queries per block (1 per wave)
  const float* pb = p + b * 12288;
  for (int i = threadIdx.x; i < 4096; i += 1024) {
    px[i] = pb[3 * i]; py[i] = pb[3 * i + 1]; pz[i] = pb[3 * i + 2];
  }
  __syncthreads();
  const int wv = threadIdx.x >> 6, lane = threadIdx.x & 63;
  const int n = nb + wv;
  const float qx = px[n], qy = py[n], qz = pz[n];
  int* row = idx + (((b << 12) + n) << 5);
  int cnt = 0, first = 0;
  for (int jb = 0; jb < 4096; jb += 128) {
    const int j0 = jb + 2 * lane;
    const float2 vx = *(const float2*)&px[j0];
    const float2 vy = *(const float2*)&py[j0];
    const float2 vz = *(const float2*)&pz[j0];
    const float dx0 = vx.x - qx, dy0 = vy.x - qy, dz0 = vz.x - qz;
    const float dx1 = vx.y - qx, dy1 = vy.y - qy, dz1 = vz.y - qz;
    // match numpy fp32 (no fma contraction, same summation order)
    const float d20 = __fadd_rn(__fadd_rn(__fmul_rn(dx0, dx0), __fmul_rn(dy0, dy0)),
                                __fmul_rn(dz0, dz0));
    const float d21 = __fadd_rn(__fadd_rn(__fmul_rn(dx1, dx1), __fmul_rn(dy1, dy1)),
                                __fmul_rn(dz1, dz1));
    const bool h0 = d20 < R2, h1 = d21 < R2;
    const unsigned long long m0 = __ballot(h0), m1 = __ballot(h1);
    if (m0 | m1) {
      if (cnt == 0) {
        const int c0 = m0 ? 2 * (int)__builtin_ctzll(m0) : 4096;
        const int c1 = m1 ? 2 * (int)__builtin_ctzll(m1) + 1 : 4096;
        first = jb + (c0 < c1 ? c0 : c1);
      }
      const unsigned long long below = (1ull << lane) - 1ull;
      const int pos0 = cnt + (int)__popcll(m0 & below) + (int)__popcll(m1 & below);
      const int pos1 = pos0 + (h0 ? 1 : 0);
      if (h0 && pos0 < 32) row[pos0] = j0;
      if (h1 && pos1 < 32) row[pos1] = j0 + 1;
      cnt += (int)__popcll(m0) + (int)__popcll(m1);
      if (cnt >= 32) break;   // uniform
    }
  }
  for (int s = cnt + lane; s < 32; s += 64) row[s] = first;
}

// ---------------- Kp: W1 transpose + W2 MFMA-fragment pack ----------------
// w2frag layout: [frag=kt*4+ot][lane][4 u32]; lane holds B[k=kt*32+(lane>>4)*8+e][o=ot*16+(lane&15)]
__global__ void k_prep(const float* __restrict__ W1, const float* __restrict__ W2,
                       float* __restrict__ W1t, uint32_t* __restrict__ w2frag) {
  const int t = blockIdx.x * 256 + threadIdx.x;   // 4096 threads
  if (t < 2240) { int o = t / 35, c = t - o * 35; W1t[(c << 6) + o] = W1[t]; }
  if (t < 2048) {
    const int e2 = t & 3, lane = (t >> 2) & 63, frag = t >> 8;
    const int kt = frag >> 2, ot = frag & 3;
    const int c0 = kt * 32 + ((lane >> 4) << 3) + e2 * 2;
    const int o = ot * 16 + (lane & 15);
    w2frag[t] = pack_bf16(W2[(o << 6) + c0], W2[(o << 6) + c0 + 1]);
  }
}

// ---------------- K2: u, q per point (8 threads/point) ----------------
__global__ __launch_bounds__(256) void k_uq(const float* __restrict__ p,
                                            const float* __restrict__ x,
                                            const float* __restrict__ W1t,
                                            float* __restrict__ u, float* __restrict__ q) {
  const int t = threadIdx.x;
  const int gb = blockIdx.x;                 // 512 blocks
  const int b = gb >> 7;
  const int n = ((gb & 127) << 5) + (t & 31);
  const int os = (t >> 5) << 3;              // 8-output slice
  const int pn = (b << 12) + n;
  float f[35];
  const float* pb = p + pn * 3;
  f[0] = pb[0]; f[1] = pb[1]; f[2] = pb[2];
  const float* xb = x + (b << 17) + n;
#pragma unroll
  for (int c = 0; c < 32; ++c) f[3 + c] = xb[c << 12];
  float acc[8];
#pragma unroll
  for (int o = 0; o < 8; ++o) acc[o] = 0.f;
#pragma unroll
  for (int c = 0; c < 35; ++c) {
    const float fc = f[c];
    const float4* wp = (const float4*)(W1t + (c << 6) + os);
    const float4 w0 = wp[0], w1 = wp[1];
    acc[0] = fmaf(w0.x, fc, acc[0]); acc[1] = fmaf(w0.y, fc, acc[1]);
    acc[2] = fmaf(w0.z, fc, acc[2]); acc[3] = fmaf(w0.w, fc, acc[3]);
    acc[4] = fmaf(w1.x, fc, acc[4]); acc[5] = fmaf(w1.y, fc, acc[5]);
    acc[6] = fmaf(w1.z, fc, acc[6]); acc[7] = fmaf(w1.w, fc, acc[7]);
    if (c == 2) {
      *(float4*)(q + (pn << 6) + os)     = make_float4(acc[0], acc[1], acc[2], acc[3]);
      *(float4*)(q + (pn << 6) + os + 4) = make_float4(acc[4], acc[5], acc[6], acc[7]);
    }
  }
  *(float4*)(u + (pn << 6) + os)     = make_float4(acc[0], acc[1], acc[2], acc[3]);
  *(float4*)(u + (pn << 6) + os + 4) = make_float4(acc[4], acc[5], acc[6], acc[7]);
}

// ---------------- K3: BN1 stats (lane = channel) ----------------
__global__ __launch_bounds__(256) void k_bn1(const float* __restrict__ u,
                                             const float* __restrict__ q,
                                             const int* __restrict__ idx,
                                             float* __restrict__ part1) {
  const int gw = (blockIdx.x << 2) + (threadIdx.x >> 6);  // 2048 waves
  const int lane = threadIdx.x & 63;
  float s1 = 0.f, s2 = 0.f;
  const int base = gw << 3;  // 8 points per wave
  for (int t = 0; t < 8; ++t) {
    const int pn = base + t;
    const float qv = q[(pn << 6) + lane];
    const int* irow = idx + (pn << 5);
    int myj = (lane < 32) ? irow[lane] : 0;
    const int bb = (pn >> 12) << 12;
#pragma unroll 8
    for (int k = 0; k < 32; ++k) {
      int jj = __shfl(myj, k);
      float y = u[((bb + jj) << 6) + lane] - qv;
      s1 += y;
      s2 = fmaf(y, y, s2);
    }
  }
  part1[lane * 2048 + gw] = s1;
  part1[(64 + lane) * 2048 + gw] = s2;
}

// ---------------- Kf: reduce partials, finalize BN affine ----------------
__global__ __launch_bounds__(128) void k_finalize(const float* __restrict__ part, int cols,
                                                  float invM, const float* __restrict__ g,
                                                  const float* __restrict__ bb,
                                                  float* __restrict__ ac) {
  const int ch = blockIdx.x;           // 64 blocks
  const int t = threadIdx.x;           // 2 waves
  const int half = t >> 6, lane = t & 63;
  const float4* r4 = (const float4*)(part + (size_t)(ch + half * 64) * cols);
  float s = 0.f;
  for (int i = lane; i < (cols >> 2); i += 64) {
    float4 v = r4[i];
    s += v.x + v.y + v.z + v.w;
  }
  for (int d = 32; d; d >>= 1) s += __shfl_xor(s, d);
  __shared__ float ls[2];
  if (lane == 0) ls[half] = s;
  __syncthreads();
  if (t == 0) {
    float mean = ls[0] * invM;
    float var = ls[1] * invM - mean * mean;
    float a = g[ch] * rsqrtf(var + 1e-5f);
    ac[ch] = a;
    ac[64 + ch] = bb[ch] - mean * a;
  }
}

// ---------------- K5: MFMA conv2 + k-reduce + BN2 partials ----------------
// block = 256 thr (4 waves), 16 points (512 samples). LDS h: [512 s][64 c] bf16,
// byte = s*128 + c*2, swizzled byte ^= (s&7)<<4 (conflict-free b128 col reads).
__global__ __launch_bounds__(256) void k_stage2(const float* __restrict__ u,
                                                const float* __restrict__ q,
                                                const int* __restrict__ idx,
                                                const float* __restrict__ a1c1,
                                                const uint32_t* __restrict__ w2frag,
                                                float* __restrict__ part2,
                                                float* __restrict__ ymax,
                                                float* __restrict__ ymin) {
  __shared__ uint32_t hl[16384];   // 64 KB
  const int tid = threadIdx.x, w = tid >> 6, l = tid & 63;
  const int blk = blockIdx.x;
  const int p0 = blk << 4;                   // global point base
  const int cs = (l >> 4) << 4;              // 16-channel slice

  // ---- phase 1: h = relu(a1*(u[j]-q[n])+c1) -> LDS bf16 (swizzled)
  f32x4 a1v[4], c1v[4];
#pragma unroll
  for (int i = 0; i < 4; ++i) {
    a1v[i] = *(const f32x4*)(a1c1 + cs + 4 * i);
    c1v[i] = *(const f32x4*)(a1c1 + 64 + cs + 4 * i);
  }
#pragma unroll 2
  for (int it = 0; it < 8; ++it) {
    const int sl = (w << 7) + (it << 4) + (l & 15);   // local sample 0..511
    const int pn = p0 + (sl >> 5);
    const int k = sl & 31;
    const int j = idx[(pn << 5) + k];
    const int bb = (pn >> 12) << 12;
    const float4* up = (const float4*)(u + ((bb + j) << 6) + cs);
    const float4* qp = (const float4*)(q + (pn << 6) + cs);
#pragma unroll
    for (int i = 0; i < 4; ++i) {
      const float4 uu = up[i], qq = qp[i];
      const f32x4 a = a1v[i], c = c1v[i];
      const float h0 = fmaxf(fmaf(a[0], uu.x - qq.x, c[0]), 0.f);
      const float h1 = fmaxf(fmaf(a[1], uu.y - qq.y, c[1]), 0.f);
      const float h2 = fmaxf(fmaf(a[2], uu.z - qq.z, c[2]), 0.f);
      const float h3 = fmaxf(fmaf(a[3], uu.w - qq.w, c[3]), 0.f);
      int byte = (sl << 7) + (cs << 1) + (i << 3);
      byte ^= (sl & 7) << 4;
      *(uint2*)((char*)hl + byte) = make_uint2(pack_bf16(h0, h1), pack_bf16(h2, h3));
    }
  }
  __syncthreads();

  // ---- phase 2: preload W2 fragments (coalesced, L2-hot)
  bf16x8 bfr[8];
#pragma unroll
  for (int f = 0; f < 8; ++f)
    bfr[f] = __builtin_bit_cast(bf16x8, *(const uint4*)&w2frag[(f << 8) + (l << 2)]);

  // ---- phase 3: per point: 16 MFMAs, stats
  float ssum[4] = {0.f, 0.f, 0.f, 0.f}, ssq[4] = {0.f, 0.f, 0.f, 0.f};
  const f32x4 zero = {0.f, 0.f, 0.f, 0.f};
#pragma unroll 1
  for (int pp = 0; pp < 4; ++pp) {
    const int ptl = (w << 2) + pp;
    bf16x8 af[2][2];  // [s-tile][k-tile]
#pragma unroll
    for (int st = 0; st < 2; ++st)
#pragma unroll
      for (int kt = 0; kt < 2; ++kt) {
        const int srow = (ptl << 5) + (st << 4) + (l & 15);
        int byte = (srow << 7) + (kt << 6) + ((l >> 4) << 4);
        byte ^= (srow & 7) << 4;
        af[st][kt] = *(const bf16x8*)((const char*)hl + byte);
      }
    const int pn = p0 + ptl;
#pragma unroll
    for (int ot = 0; ot < 4; ++ot) {
      f32x4 acc0 = zero, acc1 = zero;
      acc0 = __builtin_amdgcn_mfma_f32_16x16x32_bf16(af[0][0], bfr[ot], acc0, 0, 0, 0);
      acc0 = __builtin_amdgcn_mfma_f32_16x16x32_bf16(af[0][1], bfr[4 + ot], acc0, 0, 0, 0);
      acc1 = __builtin_amdgcn_mfma_f32_16x16x32_bf16(af[1][0], bfr[ot], acc1, 0, 0, 0);
      acc1 = __builtin_amdgcn_mfma_f32_16x16x32_bf16(af[1][1], bfr[4 + ot], acc1, 0, 0, 0);
      float mx = acc0[0], mn = acc0[0];
      float s = 0.f, t2 = 0.f;
#pragma unroll
      for (int e = 0; e < 4; ++e) {
        const float v0 = acc0[e], v1 = acc1[e];
        mx = fmaxf(mx, fmaxf(v0, v1));
        mn = fminf(mn, fminf(v0, v1));
        s += v0 + v1;
        t2 = fmaf(v0, v0, fmaf(v1, v1, t2));
      }
      ssum[ot] += s; ssq[ot] += t2;
      mx = fmaxf(mx, __shfl_xor(mx, 16)); mx = fmaxf(mx, __shfl_xor(mx, 32));
      mn = fminf(mn, __shfl_xor(mn, 16)); mn = fminf(mn, __shfl_xor(mn, 32));
      const int o = (ot << 4) + (l & 15);
      if (l < 16)      ymax[(pn << 6) + o] = mx;
      else if (l < 32) ymin[(pn << 6) + o] = mn;
    }
  }
  // ---- BN2 partials (per wave)
#pragma unroll
  for (int ot = 0; ot < 4; ++ot) {
    float s = ssum[ot]; s += __shfl_xor(s, 16); s += __shfl_xor(s, 32);
    float t2 = ssq[ot]; t2 += __shfl_xor(t2, 16); t2 += __shfl_xor(t2, 32);
    if (l < 16) {
      const int o = (ot << 4) + l;
      const int col = (blk << 2) + w;   // 4096 columns
      part2[o * 4096 + col] = s;
      part2[(64 + o) * 4096 + col] = t2;
    }
  }
}

// ---------------- K6: output ----------------
__global__ __launch_bounds__(256) void k_out(const float* __restrict__ ymax,
                                             const float* __restrict__ ymin,
                                             const float* __restrict__ ac,
                                             float* __restrict__ out) {
  const int i = blockIdx.x * 256 + threadIdx.x;  // i = pn*64 + o
  const int o = i & 63;
  const int pn = i >> 6;
  const int b = pn >> 12, n = pn & 4095;
  float a = ac[o], c = ac[64 + o];
  float v = (a >= 0.f) ? ymax[i] : ymin[i];
  out[(b << 18) + (o << 12) + n] = fmaxf(fmaf(a, v, c), 0.f);
}

extern "C" void kernel_launch(void* const* d_in, const int* in_sizes, int n_in,
                              void* d_out, int out_size, void* d_ws, size_t ws_size,
                              hipStream_t stream) {
  const float* p  = (const float*)d_in[0];
  const float* x  = (const float*)d_in[1];
  const float* W1 = (const float*)d_in[2];
  const float* g1 = (const float*)d_in[3];
  const float* b1 = (const float*)d_in[4];
  const float* W2 = (const float*)d_in[5];
  const float* g2 = (const float*)d_in[6];
  const float* b2 = (const float*)d_in[7];
  float* out = (float*)d_out;

  char* ws = (char*)d_ws;
  size_t off = 0;
  int* idx       = (int*)(ws + off);      off += 2097152;   // B*N*32 int
  float* u       = (float*)(ws + off);    off += 4194304;   // B*N*64 f32
  float* q       = (float*)(ws + off);    off += 4194304;
  float* W1t     = (float*)(ws + off);    off += 16384;
  uint32_t* w2f  = (uint32_t*)(ws + off); off += 8192;      // 8 frags * 64 lanes * 16B
  float* part1   = (float*)(ws + off);    off += 1048576;   // [128][2048]
  float* a1c1    = (float*)(ws + off);    off += 1024;
  float* part2   = (float*)(ws + off);    off += 2097152;   // [128][4096]
  float* a2c2    = (float*)(ws + off);    off += 1024;
  float* ymax    = (float*)(ws + off);    off += 4194304;   // [pn][o]
  float* ymin    = (float*)(ws + off);    off += 4194304;   // ~20.9 MB total

  const float invM = 1.f / 524288.f;

  k_ballquery<<<dim3(1024), dim3(1024), 0, stream>>>(p, idx);
  k_prep<<<dim3(16), dim3(256), 0, stream>>>(W1, W2, W1t, w2f);
  k_uq<<<dim3(512), dim3(256), 0, stream>>>(p, x, W1t, u, q);
  k_bn1<<<dim3(512), dim3(256), 0, stream>>>(u, q, idx, part1);
  k_finalize<<<dim3(64), dim3(128), 0, stream>>>(part1, 2048, invM, g1, b1, a1c1);
  k_stage2<<<dim3(1024), dim3(256), 0, stream>>>(u, q, idx, a1c1, w2f, part2, ymax, ymin);
  k_finalize<<<dim3(64), dim3(128), 0, stream>>>(part2, 4096, invM, g2, b2, a2c2);
  k_out<<<dim3(4096), dim3(256), 0, stream>>>(ymax, ymin, a2c2, out);
}

// Round 3
// 105.902 us; speedup vs baseline: 1.9919x; 1.0575x over previous
//
#include <hip/hip_runtime.h>
#include <stdint.h>

// LocalAggregation (PointNet++ SA layer, B=4 N=4096 C=32 K=32, 35->64->64)
//
//  K1 ballquery : idx[b][n][32] (first 32 ascending j with d2<0.01, pad=first)
//  Kp prep      : W1t[35][64]; W2 packed as bf16 MFMA B-fragments (8 frags)
//  K2 uq        : u[b][n][64] = W1[:,3:]x + W1[:,:3]p ; q = W1[:,:3]p  (y1 = u[j]-q[n])
//  K3 bn1 stats : per-channel sum/sumsq of y1 -> partials (XCD-local batches)
//  Kf finalize  : a1 = g/sqrt(var+eps), c1 = b - a1*mean
//  K5 stage2    : h = relu(a1*(u[j]-q[n])+c1) -> LDS bf16 (swizzled);
//                 y2 = W2*h via mfma_16x16x32_bf16 (samples on M-axis);
//                 per-(n,o) max/min over k; BN2 sum/sumsq partials
//                 (XCD-swizzled blocks so each XCD's u working set = 1 batch, L2-fit)
//  Kf finalize  : a2,c2
//  K6 out       : out[b][o][n] = relu(a2*(a2>=0?max:min) + c2), LDS 64x64 transpose

#define R2 0.01f

typedef __bf16 bf16x8 __attribute__((ext_vector_type(8)));
typedef float f32x4 __attribute__((ext_vector_type(4)));

__device__ __forceinline__ uint32_t pack_bf16(float a, float b) {
  uint32_t ua = __float_as_uint(a), ub = __float_as_uint(b);
  ua += 0x7fffu + ((ua >> 16) & 1u);
  ub += 0x7fffu + ((ub >> 16) & 1u);
  return (ua >> 16) | (ub & 0xffff0000u);
}

// ---------------- K1: ball query (transposed LDS, 2 pts/lane) ----------------
__global__ __launch_bounds__(1024) void k_ballquery(const float* __restrict__ p,
                                                    int* __restrict__ idx) {
  __shared__ float px[4096], py[4096], pz[4096];
  const int b = blockIdx.x >> 8;             // 256 blocks per batch
  const int nb = (blockIdx.x & 255) << 4;    // 16 queries per block (1 per wave)
  const float* pb = p + b * 12288;
  for (int i = threadIdx.x; i < 4096; i += 1024) {
    px[i] = pb[3 * i]; py[i] = pb[3 * i + 1]; pz[i] = pb[3 * i + 2];
  }
  __syncthreads();
  const int wv = threadIdx.x >> 6, lane = threadIdx.x & 63;
  const int n = nb + wv;
  const float qx = px[n], qy = py[n], qz = pz[n];
  int* row = idx + (((b << 12) + n) << 5);
  int cnt = 0, first = 0;
  for (int jb = 0; jb < 4096; jb += 128) {
    const int j0 = jb + 2 * lane;
    const float2 vx = *(const float2*)&px[j0];
    const float2 vy = *(const float2*)&py[j0];
    const float2 vz = *(const float2*)&pz[j0];
    const float dx0 = vx.x - qx, dy0 = vy.x - qy, dz0 = vz.x - qz;
    const float dx1 = vx.y - qx, dy1 = vy.y - qy, dz1 = vz.y - qz;
    // match numpy fp32 (no fma contraction, same summation order)
    const float d20 = __fadd_rn(__fadd_rn(__fmul_rn(dx0, dx0), __fmul_rn(dy0, dy0)),
                                __fmul_rn(dz0, dz0));
    const float d21 = __fadd_rn(__fadd_rn(__fmul_rn(dx1, dx1), __fmul_rn(dy1, dy1)),
                                __fmul_rn(dz1, dz1));
    const bool h0 = d20 < R2, h1 = d21 < R2;
    const unsigned long long m0 = __ballot(h0), m1 = __ballot(h1);
    if (m0 | m1) {
      if (cnt == 0) {
        const int c0 = m0 ? 2 * (int)__builtin_ctzll(m0) : 4096;
        const int c1 = m1 ? 2 * (int)__builtin_ctzll(m1) + 1 : 4096;
        first = jb + (c0 < c1 ? c0 : c1);
      }
      const unsigned long long below = (1ull << lane) - 1ull;
      const int pos0 = cnt + (int)__popcll(m0 & below) + (int)__popcll(m1 & below);
      const int pos1 = pos0 + (h0 ? 1 : 0);
      if (h0 && pos0 < 32) row[pos0] = j0;
      if (h1 && pos1 < 32) row[pos1] = j0 + 1;
      cnt += (int)__popcll(m0) + (int)__popcll(m1);
      if (cnt >= 32) break;   // uniform
    }
  }
  for (int s = cnt + lane; s < 32; s += 64) row[s] = first;
}

// ---------------- Kp: W1 transpose + W2 MFMA-fragment pack ----------------
// w2frag layout: [frag=kt*4+ot][lane][4 u32]; lane holds B[k=kt*32+(lane>>4)*8+e][o=ot*16+(lane&15)]
__global__ void k_prep(const float* __restrict__ W1, const float* __restrict__ W2,
                       float* __restrict__ W1t, uint32_t* __restrict__ w2frag) {
  const int t = blockIdx.x * 256 + threadIdx.x;   // 4096 threads
  if (t < 2240) { int o = t / 35, c = t - o * 35; W1t[(c << 6) + o] = W1[t]; }
  if (t < 2048) {
    const int e2 = t & 3, lane = (t >> 2) & 63, frag = t >> 8;
    const int kt = frag >> 2, ot = frag & 3;
    const int c0 = kt * 32 + ((lane >> 4) << 3) + e2 * 2;
    const int o = ot * 16 + (lane & 15);
    w2frag[t] = pack_bf16(W2[(o << 6) + c0], W2[(o << 6) + c0 + 1]);
  }
}

// ---------------- K2: u, q per point (8 threads/point) ----------------
__global__ __launch_bounds__(256) void k_uq(const float* __restrict__ p,
                                            const float* __restrict__ x,
                                            const float* __restrict__ W1t,
                                            float* __restrict__ u, float* __restrict__ q) {
  const int t = threadIdx.x;
  const int gb = blockIdx.x;                 // 512 blocks
  const int b = gb >> 7;
  const int n = ((gb & 127) << 5) + (t & 31);
  const int os = (t >> 5) << 3;              // 8-output slice
  const int pn = (b << 12) + n;
  float f[35];
  const float* pb = p + pn * 3;
  f[0] = pb[0]; f[1] = pb[1]; f[2] = pb[2];
  const float* xb = x + (b << 17) + n;
#pragma unroll
  for (int c = 0; c < 32; ++c) f[3 + c] = xb[c << 12];
  float acc[8];
#pragma unroll
  for (int o = 0; o < 8; ++o) acc[o] = 0.f;
#pragma unroll
  for (int c = 0; c < 35; ++c) {
    const float fc = f[c];
    const float4* wp = (const float4*)(W1t + (c << 6) + os);
    const float4 w0 = wp[0], w1 = wp[1];
    acc[0] = fmaf(w0.x, fc, acc[0]); acc[1] = fmaf(w0.y, fc, acc[1]);
    acc[2] = fmaf(w0.z, fc, acc[2]); acc[3] = fmaf(w0.w, fc, acc[3]);
    acc[4] = fmaf(w1.x, fc, acc[4]); acc[5] = fmaf(w1.y, fc, acc[5]);
    acc[6] = fmaf(w1.z, fc, acc[6]); acc[7] = fmaf(w1.w, fc, acc[7]);
    if (c == 2) {
      *(float4*)(q + (pn << 6) + os)     = make_float4(acc[0], acc[1], acc[2], acc[3]);
      *(float4*)(q + (pn << 6) + os + 4) = make_float4(acc[4], acc[5], acc[6], acc[7]);
    }
  }
  *(float4*)(u + (pn << 6) + os)     = make_float4(acc[0], acc[1], acc[2], acc[3]);
  *(float4*)(u + (pn << 6) + os + 4) = make_float4(acc[4], acc[5], acc[6], acc[7]);
}

// ---------------- K3: BN1 stats (lane = channel, XCD-local batch) ----------------
__global__ __launch_bounds__(256) void k_bn1(const float* __restrict__ u,
                                             const float* __restrict__ q,
                                             const int* __restrict__ idx,
                                             float* __restrict__ part1) {
  // bijective swizzle: XCD x (= blockIdx%8) gets contiguous point range -> L2-local batch
  const int blk = ((blockIdx.x & 7) << 6) + (blockIdx.x >> 3);   // 512 blocks
  const int gw = (blk << 2) + (threadIdx.x >> 6);                // 2048 waves
  const int lane = threadIdx.x & 63;
  float s1 = 0.f, s2 = 0.f;
  const int base = gw << 3;  // 8 points per wave
  for (int t = 0; t < 8; ++t) {
    const int pn = base + t;
    const float qv = q[(pn << 6) + lane];
    const int* irow = idx + (pn << 5);
    int myj = (lane < 32) ? irow[lane] : 0;
    const int bb = (pn >> 12) << 12;
#pragma unroll 8
    for (int k = 0; k < 32; ++k) {
      int jj = __shfl(myj, k);
      float y = u[((bb + jj) << 6) + lane] - qv;
      s1 += y;
      s2 = fmaf(y, y, s2);
    }
  }
  part1[lane * 2048 + gw] = s1;
  part1[(64 + lane) * 2048 + gw] = s2;
}

// ---------------- Kf: reduce partials, finalize BN affine ----------------
__global__ __launch_bounds__(128) void k_finalize(const float* __restrict__ part, int cols,
                                                  float invM, const float* __restrict__ g,
                                                  const float* __restrict__ bb,
                                                  float* __restrict__ ac) {
  const int ch = blockIdx.x;           // 64 blocks
  const int t = threadIdx.x;           // 2 waves
  const int half = t >> 6, lane = t & 63;
  const float4* r4 = (const float4*)(part + (size_t)(ch + half * 64) * cols);
  float s = 0.f;
  for (int i = lane; i < (cols >> 2); i += 64) {
    float4 v = r4[i];
    s += v.x + v.y + v.z + v.w;
  }
  for (int d = 32; d; d >>= 1) s += __shfl_xor(s, d);
  __shared__ float ls[2];
  if (lane == 0) ls[half] = s;
  __syncthreads();
  if (t == 0) {
    float mean = ls[0] * invM;
    float var = ls[1] * invM - mean * mean;
    float a = g[ch] * rsqrtf(var + 1e-5f);
    ac[ch] = a;
    ac[64 + ch] = bb[ch] - mean * a;
  }
}

// ---------------- K5: MFMA conv2 + k-reduce + BN2 partials ----------------
// block = 256 thr (4 waves), 8 points (256 samples), 32 KB LDS (5 blocks/CU).
// LDS h: [256 s][64 c] bf16, byte = s*128 + c*2, swizzled byte ^= (s&7)<<4
// (conflict-free b128 column reads). XCD-swizzled blocks: per-XCD u set = 2 MB.
__global__ __launch_bounds__(256) void k_stage2(const float* __restrict__ u,
                                                const float* __restrict__ q,
                                                const int* __restrict__ idx,
                                                const float* __restrict__ a1c1,
                                                const uint32_t* __restrict__ w2frag,
                                                float* __restrict__ part2,
                                                float* __restrict__ ymax,
                                                float* __restrict__ ymin) {
  __shared__ uint32_t hl[8192];   // 32 KB
  const int tid = threadIdx.x, w = tid >> 6, l = tid & 63;
  const int blk0 = blockIdx.x;                       // 2048 blocks
  const int blk = ((blk0 & 7) << 8) + (blk0 >> 3);   // bijective XCD swizzle
  const int p0 = blk << 3;                           // global point base (8 pts)
  const int cs = (l >> 4) << 4;                      // 16-channel slice

  // ---- phase 1: h = relu(a1*(u[j]-q[n])+c1) -> LDS bf16 (swizzled)
  f32x4 a1v[4], c1v[4];
#pragma unroll
  for (int i = 0; i < 4; ++i) {
    a1v[i] = *(const f32x4*)(a1c1 + cs + 4 * i);
    c1v[i] = *(const f32x4*)(a1c1 + 64 + cs + 4 * i);
  }
#pragma unroll
  for (int it = 0; it < 4; ++it) {
    const int sl = (w << 6) + (it << 4) + (l & 15);   // local sample 0..255
    const int pn = p0 + (sl >> 5);
    const int k = sl & 31;
    const int j = idx[(pn << 5) + k];
    const int bb = (pn >> 12) << 12;
    const float4* up = (const float4*)(u + ((bb + j) << 6) + cs);
    const float4* qp = (const float4*)(q + (pn << 6) + cs);
#pragma unroll
    for (int i = 0; i < 4; ++i) {
      const float4 uu = up[i], qq = qp[i];
      const f32x4 a = a1v[i], c = c1v[i];
      const float h0 = fmaxf(fmaf(a[0], uu.x - qq.x, c[0]), 0.f);
      const float h1 = fmaxf(fmaf(a[1], uu.y - qq.y, c[1]), 0.f);
      const float h2 = fmaxf(fmaf(a[2], uu.z - qq.z, c[2]), 0.f);
      const float h3 = fmaxf(fmaf(a[3], uu.w - qq.w, c[3]), 0.f);
      int byte = (sl << 7) + (cs << 1) + (i << 3);
      byte ^= (sl & 7) << 4;
      *(uint2*)((char*)hl + byte) = make_uint2(pack_bf16(h0, h1), pack_bf16(h2, h3));
    }
  }
  __syncthreads();

  // ---- phase 2: preload W2 fragments (coalesced, L2-hot)
  bf16x8 bfr[8];
#pragma unroll
  for (int f = 0; f < 8; ++f)
    bfr[f] = __builtin_bit_cast(bf16x8, *(const uint4*)&w2frag[(f << 8) + (l << 2)]);

  // ---- phase 3: per point: 16 MFMAs, stats
  float ssum[4] = {0.f, 0.f, 0.f, 0.f}, ssq[4] = {0.f, 0.f, 0.f, 0.f};
  const f32x4 zero = {0.f, 0.f, 0.f, 0.f};
#pragma unroll 1
  for (int pp = 0; pp < 2; ++pp) {
    const int ptl = (w << 1) + pp;
    bf16x8 af[2][2];  // [s-tile][k-tile]
#pragma unroll
    for (int st = 0; st < 2; ++st)
#pragma unroll
      for (int kt = 0; kt < 2; ++kt) {
        const int srow = (ptl << 5) + (st << 4) + (l & 15);
        int byte = (srow << 7) + (kt << 6) + ((l >> 4) << 4);
        byte ^= (srow & 7) << 4;
        af[st][kt] = *(const bf16x8*)((const char*)hl + byte);
      }
    const int pn = p0 + ptl;
#pragma unroll
    for (int ot = 0; ot < 4; ++ot) {
      f32x4 acc0 = zero, acc1 = zero;
      acc0 = __builtin_amdgcn_mfma_f32_16x16x32_bf16(af[0][0], bfr[ot], acc0, 0, 0, 0);
      acc0 = __builtin_amdgcn_mfma_f32_16x16x32_bf16(af[0][1], bfr[4 + ot], acc0, 0, 0, 0);
      acc1 = __builtin_amdgcn_mfma_f32_16x16x32_bf16(af[1][0], bfr[ot], acc1, 0, 0, 0);
      acc1 = __builtin_amdgcn_mfma_f32_16x16x32_bf16(af[1][1], bfr[4 + ot], acc1, 0, 0, 0);
      float mx = acc0[0], mn = acc0[0];
      float s = 0.f, t2 = 0.f;
#pragma unroll
      for (int e = 0; e < 4; ++e) {
        const float v0 = acc0[e], v1 = acc1[e];
        mx = fmaxf(mx, fmaxf(v0, v1));
        mn = fminf(mn, fminf(v0, v1));
        s += v0 + v1;
        t2 = fmaf(v0, v0, fmaf(v1, v1, t2));
      }
      ssum[ot] += s; ssq[ot] += t2;
      mx = fmaxf(mx, __shfl_xor(mx, 16)); mx = fmaxf(mx, __shfl_xor(mx, 32));
      mn = fminf(mn, __shfl_xor(mn, 16)); mn = fminf(mn, __shfl_xor(mn, 32));
      const int o = (ot << 4) + (l & 15);
      if (l < 16)      ymax[(pn << 6) + o] = mx;
      else if (l < 32) ymin[(pn << 6) + o] = mn;
    }
  }
  // ---- BN2 partials (per wave)
#pragma unroll
  for (int ot = 0; ot < 4; ++ot) {
    float s = ssum[ot]; s += __shfl_xor(s, 16); s += __shfl_xor(s, 32);
    float t2 = ssq[ot]; t2 += __shfl_xor(t2, 16); t2 += __shfl_xor(t2, 32);
    if (l < 16) {
      const int o = (ot << 4) + l;
      const int col = (blk0 << 2) + w;   // 8192 columns
      part2[o * 8192 + col] = s;
      part2[(64 + o) * 8192 + col] = t2;
    }
  }
}

// ---------------- K6: output (LDS 64x64 transpose, coalesced both ways) ----------------
__global__ __launch_bounds__(256) void k_out(const float* __restrict__ ymax,
                                             const float* __restrict__ ymin,
                                             const float* __restrict__ ac,
                                             float* __restrict__ out) {
  __shared__ float tile[64][65];
  const int b = blockIdx.x >> 6, nt = blockIdx.x & 63;   // 256 blocks
  const int tid = threadIdx.x;
  const int pnbase = (b << 12) + (nt << 6);
#pragma unroll
  for (int i = 0; i < 16; ++i) {
    const int e = i * 256 + tid;
    const int nl = e >> 6, o = e & 63;
    const float a = ac[o], c = ac[64 + o];
    const int src = ((pnbase + nl) << 6) + o;
    const float v = (a >= 0.f) ? ymax[src] : ymin[src];
    tile[nl][o] = fmaxf(fmaf(a, v, c), 0.f);
  }
  __syncthreads();
#pragma unroll
  for (int i = 0; i < 16; ++i) {
    const int e = i * 256 + tid;
    const int ol = e >> 6, nl = e & 63;
    out[(b << 18) + (ol << 12) + (nt << 6) + nl] = tile[nl][ol];
  }
}

extern "C" void kernel_launch(void* const* d_in, const int* in_sizes, int n_in,
                              void* d_out, int out_size, void* d_ws, size_t ws_size,
                              hipStream_t stream) {
  const float* p  = (const float*)d_in[0];
  const float* x  = (const float*)d_in[1];
  const float* W1 = (const float*)d_in[2];
  const float* g1 = (const float*)d_in[3];
  const float* b1 = (const float*)d_in[4];
  const float* W2 = (const float*)d_in[5];
  const float* g2 = (const float*)d_in[6];
  const float* b2 = (const float*)d_in[7];
  float* out = (float*)d_out;

  char* ws = (char*)d_ws;
  size_t off = 0;
  int* idx       = (int*)(ws + off);      off += 2097152;   // B*N*32 int
  float* u       = (float*)(ws + off);    off += 4194304;   // B*N*64 f32
  float* q       = (float*)(ws + off);    off += 4194304;
  float* W1t     = (float*)(ws + off);    off += 16384;
  uint32_t* w2f  = (uint32_t*)(ws + off); off += 8192;      // 8 frags * 64 lanes * 16B
  float* part1   = (float*)(ws + off);    off += 1048576;   // [128][2048]
  float* a1c1    = (float*)(ws + off);    off += 1024;
  float* part2   = (float*)(ws + off);    off += 4194304;   // [128][8192]
  float* a2c2    = (float*)(ws + off);    off += 1024;
  float* ymax    = (float*)(ws + off);    off += 4194304;   // [pn][o]
  float* ymin    = (float*)(ws + off);    off += 4194304;   // ~23 MB total

  const float invM = 1.f / 524288.f;

  k_ballquery<<<dim3(1024), dim3(1024), 0, stream>>>(p, idx);
  k_prep<<<dim3(16), dim3(256), 0, stream>>>(W1, W2, W1t, w2f);
  k_uq<<<dim3(512), dim3(256), 0, stream>>>(p, x, W1t, u, q);
  k_bn1<<<dim3(512), dim3(256), 0, stream>>>(u, q, idx, part1);
  k_finalize<<<dim3(64), dim3(128), 0, stream>>>(part1, 2048, invM, g1, b1, a1c1);
  k_stage2<<<dim3(2048), dim3(256), 0, stream>>>(u, q, idx, a1c1, w2f, part2, ymax, ymin);
  k_finalize<<<dim3(64), dim3(128), 0, stream>>>(part2, 8192, invM, g2, b2, a2c2);
  k_out<<<dim3(256), dim3(256), 0, stream>>>(ymax, ymin, a2c2, out);
}